// Round 4
// baseline (109.796 us; speedup 1.0000x reference)
//
#include <hip/hip_runtime.h>

#define WEIGHT_POSITIVE 0.1f

__device__ __forceinline__ float wmse4(float4 p, int4 t) {
    float a;
    {
        float d  = p.x - (float)t.x;
        bool mis = (p.x >= 0.5f) != (t.x == 1);
        a  = (mis ? 1.1f : 1.0f) * d * d;
    }
    {
        float d  = p.y - (float)t.y;
        bool mis = (p.y >= 0.5f) != (t.y == 1);
        a += (mis ? 1.1f : 1.0f) * d * d;
    }
    {
        float d  = p.z - (float)t.z;
        bool mis = (p.z >= 0.5f) != (t.z == 1);
        a += (mis ? 1.1f : 1.0f) * d * d;
    }
    {
        float d  = p.w - (float)t.w;
        bool mis = (p.w >= 0.5f) != (t.w == 1);
        a += (mis ? 1.1f : 1.0f) * d * d;
    }
    return a;
}

// Fused single-dispatch reduction: block-contiguous chunks + last-block-done
// final reduce (threadfence-reduction pattern). Output is bitwise-deterministic:
// each block's partial is a fixed-order sum, and the last block sums partials
// in fixed index order regardless of which block arrives last.
__global__ __launch_bounds__(256) void wmse_fused(
    const float* __restrict__ pred,
    const int* __restrict__ tgt,
    float* __restrict__ partial,      // [gridDim.x] in d_ws
    unsigned int* __restrict__ ticket, // zeroed via hipMemsetAsync each launch
    float* __restrict__ out,
    int vec_per_block,
    int n_vec,
    int n,
    float inv_n)
{
    const float4* __restrict__ p4 = reinterpret_cast<const float4*>(pred);
    const int4*   __restrict__ t4 = reinterpret_cast<const int4*>(tgt);

    const int start = blockIdx.x * vec_per_block;
    int end = start + vec_per_block;
    if (end > n_vec) end = n_vec;

    float acc = 0.0f;

    for (int i = start + threadIdx.x; i < end; i += 256) {
        acc += wmse4(p4[i], t4[i]);
    }

    // scalar tail (n not divisible by 4) — block 0
    if (blockIdx.x == 0) {
        for (int k = n_vec * 4 + threadIdx.x; k < n; k += 256) {
            float p  = pred[k];
            int   t  = tgt[k];
            float d  = p - (float)t;
            bool mis = (p >= 0.5f) != (t == 1);
            acc += (mis ? 1.1f : 1.0f) * d * d;
        }
    }

    // wave-64 reduction
    #pragma unroll
    for (int off = 32; off > 0; off >>= 1)
        acc += __shfl_down(acc, off, 64);

    __shared__ float s[4];  // 4 waves
    __shared__ unsigned int s_rank;
    const int lane = threadIdx.x & 63;
    const int wave = threadIdx.x >> 6;
    if (lane == 0) s[wave] = acc;
    __syncthreads();

    if (threadIdx.x == 0) {
        partial[blockIdx.x] = s[0] + s[1] + s[2] + s[3];
        __threadfence();                       // release: partial visible device-wide
        s_rank = atomicAdd(ticket, 1u);        // device-scope (G12/m20)
    }
    __syncthreads();

    if (s_rank != gridDim.x - 1) return;       // not the last block

    // last block: acquire, then reduce all partials in fixed order
    __threadfence();

    const float4* __restrict__ pp4 = reinterpret_cast<const float4*>(partial);
    const int nb4 = (int)(gridDim.x / 4);      // gridDim.x is a multiple of 4

    float facc = 0.0f;
    for (int i = threadIdx.x; i < nb4; i += 256) {
        float4 v = pp4[i];
        facc += (v.x + v.y) + (v.z + v.w);
    }

    #pragma unroll
    for (int off = 32; off > 0; off >>= 1)
        facc += __shfl_down(facc, off, 64);

    __shared__ float fs[4];
    if (lane == 0) fs[wave] = facc;
    __syncthreads();

    if (threadIdx.x == 0)
        out[0] = (fs[0] + fs[1] + fs[2] + fs[3]) * inv_n;
}

extern "C" void kernel_launch(void* const* d_in, const int* in_sizes, int n_in,
                              void* d_out, int out_size, void* d_ws, size_t ws_size,
                              hipStream_t stream) {
    const float* pred = (const float*)d_in[0];
    const int*   tgt  = (const int*)d_in[1];
    float*       out  = (float*)d_out;

    const int n     = in_sizes[0];
    const int n_vec = n / 4;

    const int blocks = 2048;  // multiple of 4; 8 blocks/CU
    const int vec_per_block = (n_vec + blocks - 1) / blocks;

    float*        partial = (float*)d_ws;
    unsigned int* ticket  = (unsigned int*)((char*)d_ws + blocks * sizeof(float));

    // zero the ticket counter (d_ws is poisoned 0xAA and never re-poisoned)
    hipMemsetAsync(ticket, 0, sizeof(unsigned int), stream);

    wmse_fused<<<blocks, 256, 0, stream>>>(pred, tgt, partial, ticket, out,
                                           vec_per_block, n_vec, n,
                                           1.0f / (float)n);
}

// Round 5
// 46.859 us; speedup vs baseline: 2.3431x; 2.3431x over previous
//
#include <hip/hip_runtime.h>

#define WEIGHT_POSITIVE 0.1f

__device__ __forceinline__ float wmse4(float4 p, int4 t) {
    float a;
    {
        float d  = p.x - (float)t.x;
        bool mis = (p.x >= 0.5f) != (t.x == 1);
        a  = (mis ? 1.1f : 1.0f) * d * d;
    }
    {
        float d  = p.y - (float)t.y;
        bool mis = (p.y >= 0.5f) != (t.y == 1);
        a += (mis ? 1.1f : 1.0f) * d * d;
    }
    {
        float d  = p.z - (float)t.z;
        bool mis = (p.z >= 0.5f) != (t.z == 1);
        a += (mis ? 1.1f : 1.0f) * d * d;
    }
    {
        float d  = p.w - (float)t.w;
        bool mis = (p.w >= 0.5f) != (t.w == 1);
        a += (mis ? 1.1f : 1.0f) * d * d;
    }
    return a;
}

// Pass 1: each block owns a contiguous chunk of vec4 groups; threads sweep it
// coalesced (lane i reads base + i*16B). One float partial per block.
// NOTE (R4 post-mortem): do NOT fuse with a last-block-done ticket — 2048
// same-address device-scope atomics + per-block __threadfence() cost ~60 µs
// on MI355X (measured 47->110 µs regression). Two dispatches are cheaper.
__global__ __launch_bounds__(256) void wmse_partial(
    const float* __restrict__ pred,
    const int* __restrict__ tgt,
    float* __restrict__ partial,
    int vec_per_block,
    int n_vec,
    int n)
{
    const float4* __restrict__ p4 = reinterpret_cast<const float4*>(pred);
    const int4*   __restrict__ t4 = reinterpret_cast<const int4*>(tgt);

    const int start = blockIdx.x * vec_per_block;
    int end = start + vec_per_block;
    if (end > n_vec) end = n_vec;

    float acc = 0.0f;

    for (int i = start + threadIdx.x; i < end; i += 256) {
        acc += wmse4(p4[i], t4[i]);
    }

    // scalar tail (n not divisible by 4) — handled by block 0
    if (blockIdx.x == 0) {
        for (int k = n_vec * 4 + threadIdx.x; k < n; k += 256) {
            float p  = pred[k];
            int   t  = tgt[k];
            float d  = p - (float)t;
            bool mis = (p >= 0.5f) != (t == 1);
            acc += (mis ? 1.1f : 1.0f) * d * d;
        }
    }

    // wave-64 reduction
    #pragma unroll
    for (int off = 32; off > 0; off >>= 1)
        acc += __shfl_down(acc, off, 64);

    __shared__ float s[4];  // 256 threads = 4 waves
    const int lane = threadIdx.x & 63;
    const int wave = threadIdx.x >> 6;
    if (lane == 0) s[wave] = acc;
    __syncthreads();

    if (threadIdx.x == 0)
        partial[blockIdx.x] = s[0] + s[1] + s[2] + s[3];
}

// Pass 2: one 256-thread block reduces all partials (float4 loads), writes mean.
__global__ __launch_bounds__(256) void wmse_final(
    const float* __restrict__ partial,
    int nb,          // multiple of 4 guaranteed by launcher
    float* __restrict__ out,
    float inv_n)
{
    const float4* __restrict__ p4 = reinterpret_cast<const float4*>(partial);
    const int nb4 = nb / 4;

    float acc = 0.0f;
    for (int i = threadIdx.x; i < nb4; i += 256) {
        float4 v = p4[i];
        acc += (v.x + v.y) + (v.z + v.w);
    }

    #pragma unroll
    for (int off = 32; off > 0; off >>= 1)
        acc += __shfl_down(acc, off, 64);

    __shared__ float s[4];
    const int lane = threadIdx.x & 63;
    const int wave = threadIdx.x >> 6;
    if (lane == 0) s[wave] = acc;
    __syncthreads();

    if (threadIdx.x == 0)
        out[0] = (s[0] + s[1] + s[2] + s[3]) * inv_n;
}

extern "C" void kernel_launch(void* const* d_in, const int* in_sizes, int n_in,
                              void* d_out, int out_size, void* d_ws, size_t ws_size,
                              hipStream_t stream) {
    const float* pred = (const float*)d_in[0];
    const int*   tgt  = (const int*)d_in[1];
    float*       out  = (float*)d_out;
    float*       ws   = (float*)d_ws;

    const int n     = in_sizes[0];
    const int n_vec = n / 4;

    const int blocks = 2048;  // 8 blocks/CU, fills all 32 waves/CU
    const int vec_per_block = (n_vec + blocks - 1) / blocks;

    wmse_partial<<<blocks, 256, 0, stream>>>(pred, tgt, ws, vec_per_block, n_vec, n);
    wmse_final<<<1, 256, 0, stream>>>(ws, blocks, out, 1.0f / (float)n);
}